// Round 1
// baseline (222.758 us; speedup 1.0000x reference)
//
#include <hip/hip_runtime.h>
#include <math.h>

// NetVLAD: B=64, N=1024, D=512, K=64, G=16 (C=80)
#define BB 64
#define NN 1024
#define DD 512
#define KK 64
#define CC 80

// ---------------------------------------------------------------------------
// K1: scores = x @ clusters, BN(running stats), softmax over 80, keep first 64
//     -> assign (B*N, 64), per-block column sums -> asum_part
// Block: 256 threads, tile 128 rows x 80 cols, K-chunks of 32.
// ---------------------------------------------------------------------------
__global__ __launch_bounds__(256) void k_assign(
    const float* __restrict__ x,         // (B*N, D)
    const float* __restrict__ clusters,  // (D, C)
    const float* __restrict__ rmean,     // (C)
    const float* __restrict__ rvar,      // (C)
    float* __restrict__ assign,          // (B*N, K)
    float* __restrict__ asum_part)       // (512, K) per-block partials
{
    union Sm {
        struct { float xs[128][33]; float cs[32][81]; } g;       // GEMM tiles
        struct { float ss[128][81]; float rmax[128]; float rinv[128]; } s; // softmax
    };
    __shared__ Sm sm;
    __shared__ float bnm[CC], bns[CC];
    __shared__ float colp[4][64];

    const int t = threadIdx.x;
    const int row0 = blockIdx.x * 128;   // 128 rows per block; 8 blocks per b

    if (t < CC) {
        bnm[t] = rmean[t];
        bns[t] = rsqrtf(rvar[t] + 1e-5f);
    }

    const int ty = t >> 4;   // 0..15 -> rows ty*8..ty*8+7
    const int tx = t & 15;   // 0..15 -> cols tx*5..tx*5+4

    float acc[8][5];
#pragma unroll
    for (int i = 0; i < 8; ++i)
#pragma unroll
        for (int j = 0; j < 5; ++j) acc[i][j] = 0.f;

    for (int d0 = 0; d0 < DD; d0 += 32) {
        __syncthreads();
        // x tile: 128 rows x 32 d = 1024 float4
#pragma unroll
        for (int i = 0; i < 4; ++i) {
            int f = t + i * 256;
            int r = f >> 3, dq = f & 7;
            float4 v = *(const float4*)(x + (size_t)(row0 + r) * DD + d0 + dq * 4);
            sm.g.xs[r][dq * 4 + 0] = v.x;
            sm.g.xs[r][dq * 4 + 1] = v.y;
            sm.g.xs[r][dq * 4 + 2] = v.z;
            sm.g.xs[r][dq * 4 + 3] = v.w;
        }
        // clusters tile: 32 d x 80 c = 640 float4
        for (int f = t; f < 640; f += 256) {
            int d = f / 20, cq = f % 20;
            float4 v = *(const float4*)(clusters + (size_t)(d0 + d) * CC + cq * 4);
            sm.g.cs[d][cq * 4 + 0] = v.x;
            sm.g.cs[d][cq * 4 + 1] = v.y;
            sm.g.cs[d][cq * 4 + 2] = v.z;
            sm.g.cs[d][cq * 4 + 3] = v.w;
        }
        __syncthreads();
#pragma unroll 4
        for (int d = 0; d < 32; ++d) {
            float a[8], bv[5];
#pragma unroll
            for (int i = 0; i < 8; ++i) a[i] = sm.g.xs[ty * 8 + i][d];
#pragma unroll
            for (int j = 0; j < 5; ++j) bv[j] = sm.g.cs[d][tx * 5 + j];
#pragma unroll
            for (int i = 0; i < 8; ++i)
#pragma unroll
                for (int j = 0; j < 5; ++j)
                    acc[i][j] = fmaf(a[i], bv[j], acc[i][j]);
        }
    }
    __syncthreads();   // GEMM tiles dead; reuse LDS for scores

    // BN transform, stage scores
#pragma unroll
    for (int i = 0; i < 8; ++i) {
        int r = ty * 8 + i;
#pragma unroll
        for (int j = 0; j < 5; ++j) {
            int c = tx * 5 + j;
            sm.s.ss[r][c] = (acc[i][j] - bnm[c]) * bns[c];
        }
    }
    __syncthreads();
    // per-row max & 1/sum over all 80 clusters
    if (t < 128) {
        float m = -1e30f;
        for (int c = 0; c < CC; ++c) m = fmaxf(m, sm.s.ss[t][c]);
        float sum = 0.f;
        for (int c = 0; c < CC; ++c) sum += __expf(sm.s.ss[t][c] - m);
        sm.s.rmax[t] = m;
        sm.s.rinv[t] = 1.f / sum;
    }
    __syncthreads();
    // write assign (first 64 cols) coalesced + column partial sums
    const int kcol = t & 63;
    const int rg = t >> 6;   // 0..3
    float csum = 0.f;
#pragma unroll 4
    for (int rr = 0; rr < 32; ++rr) {
        int r = rg + rr * 4;
        float v = __expf(sm.s.ss[r][kcol] - sm.s.rmax[r]) * sm.s.rinv[r];
        assign[(size_t)(row0 + r) * KK + kcol] = v;
        csum += v;
    }
    colp[rg][kcol] = csum;
    __syncthreads();
    if (t < 64) {
        float s = colp[0][t] + colp[1][t] + colp[2][t] + colp[3][t];
        asum_part[(size_t)blockIdx.x * KK + t] = s;
    }
}

// ---------------------------------------------------------------------------
// K1b: a_sum[b,k] = sum of 8 row-tile partials (deterministic, no atomics)
// ---------------------------------------------------------------------------
__global__ __launch_bounds__(256) void k_asum_reduce(
    const float* __restrict__ asum_part, float* __restrict__ a_sum)
{
    int i = blockIdx.x * 256 + threadIdx.x;   // 4096 = B*K
    if (i >= BB * KK) return;
    int b = i >> 6, k = i & 63;
    float s = 0.f;
#pragma unroll
    for (int tile = 0; tile < 8; ++tile)
        s += asum_part[(size_t)(b * 8 + tile) * KK + k];
    a_sum[i] = s;
}

// ---------------------------------------------------------------------------
// K2: vlad[k,d] = sum_n assign[n,k]*x[n,d] - a_sum[k]*c2[k,d], then
//     intra-norm over k (per d), staged coalesced write, global-sumsq partial.
// Block = (b, d-tile of 128). 256 threads, acc[8][4].
// ---------------------------------------------------------------------------
__global__ __launch_bounds__(256) void k_vlad(
    const float* __restrict__ x,       // (B*N, D)
    const float* __restrict__ assign,  // (B*N, K)
    const float* __restrict__ a_sum,   // (B, K)
    const float* __restrict__ c2,      // (K, D)
    float* __restrict__ out,           // (B, D*K)
    float* __restrict__ gsum_part)     // (B*4)
{
    union Sm {
        struct { float as[32][68]; float xs[32][132]; } g;               // GEMM tiles
        struct { float red[8][128]; float sc[128]; float ot[128][65]; } e; // epilogue
    };
    __shared__ Sm sm;

    const int t = threadIdx.x;
    const int b = blockIdx.x >> 2;
    const int dt = blockIdx.x & 3;
    const int d0 = dt * 128;

    const int tx = t & 31;   // d cols tx*4..+3
    const int ty = t >> 5;   // 0..7 -> k rows ty*8..+7

    float acc[8][4];
#pragma unroll
    for (int i = 0; i < 8; ++i)
#pragma unroll
        for (int j = 0; j < 4; ++j) acc[i][j] = 0.f;

    const size_t xbase = (size_t)b * NN * DD + d0;
    const size_t abase = (size_t)b * NN * KK;

    for (int n0 = 0; n0 < NN; n0 += 32) {
        __syncthreads();
        // assign tile 32 x 64 = 512 float4
#pragma unroll
        for (int i = 0; i < 2; ++i) {
            int f = t + i * 256;
            int n = f >> 4, kq = f & 15;
            float4 v = *(const float4*)(assign + abase + (size_t)(n0 + n) * KK + kq * 4);
            *(float4*)&sm.g.as[n][kq * 4] = v;
        }
        // x tile 32 x 128 = 1024 float4
#pragma unroll
        for (int i = 0; i < 4; ++i) {
            int f = t + i * 256;
            int n = f >> 5, dq = f & 31;
            float4 v = *(const float4*)(x + xbase + (size_t)(n0 + n) * DD + dq * 4);
            *(float4*)&sm.g.xs[n][dq * 4] = v;
        }
        __syncthreads();
#pragma unroll 4
        for (int n = 0; n < 32; ++n) {
            float4 a0 = *(const float4*)&sm.g.as[n][ty * 8];
            float4 a1 = *(const float4*)&sm.g.as[n][ty * 8 + 4];
            float4 bv = *(const float4*)&sm.g.xs[n][tx * 4];
            float a[8] = {a0.x, a0.y, a0.z, a0.w, a1.x, a1.y, a1.z, a1.w};
            float bb[4] = {bv.x, bv.y, bv.z, bv.w};
#pragma unroll
            for (int i = 0; i < 8; ++i)
#pragma unroll
                for (int j = 0; j < 4; ++j)
                    acc[i][j] = fmaf(a[i], bb[j], acc[i][j]);
        }
    }
    __syncthreads();   // GEMM tiles dead; LDS now epilogue layout

    // subtract a_sum[k]*c2[k,d]
    float val[8][4];
#pragma unroll
    for (int i = 0; i < 8; ++i) {
        int k = ty * 8 + i;
        float asv = a_sum[b * KK + k];
        float4 cv = *(const float4*)(c2 + (size_t)k * DD + d0 + tx * 4);
        val[i][0] = acc[i][0] - asv * cv.x;
        val[i][1] = acc[i][1] - asv * cv.y;
        val[i][2] = acc[i][2] - asv * cv.z;
        val[i][3] = acc[i][3] - asv * cv.w;
    }
    // per-d sum of squares over k: 8 ty-group partials, then reduce
    float p[4] = {0.f, 0.f, 0.f, 0.f};
#pragma unroll
    for (int i = 0; i < 8; ++i)
#pragma unroll
        for (int j = 0; j < 4; ++j) p[j] += val[i][j] * val[i][j];
    *(float4*)&sm.e.red[ty][tx * 4] = make_float4(p[0], p[1], p[2], p[3]);
    __syncthreads();
    if (t < 128) {
        float s = 0.f;
#pragma unroll
        for (int g = 0; g < 8; ++g) s += sm.e.red[g][t];
        float scale = 1.f / fmaxf(sqrtf(s), 1e-12f);
        sm.e.sc[t] = scale;
        sm.e.red[0][t] = s * scale * scale;  // column contribution to global sumsq
    }
    __syncthreads();
    if (t == 0) {
        float s = 0.f;
        for (int d = 0; d < 128; ++d) s += sm.e.red[0][d];
        gsum_part[blockIdx.x] = s;
    }
    // scale + stage transposed (d-major, k-minor) for coalesced write
#pragma unroll
    for (int i = 0; i < 8; ++i)
#pragma unroll
        for (int j = 0; j < 4; ++j)
            sm.e.ot[tx * 4 + j][ty * 8 + i] = val[i][j] * sm.e.sc[tx * 4 + j];
    __syncthreads();
    const size_t obase = (size_t)b * (DD * KK) + (size_t)d0 * KK;
#pragma unroll
    for (int i = 0; i < 32; ++i) {
        int f = t + i * 256;
        out[obase + f] = sm.e.ot[f >> 6][f & 63];
    }
}

// ---------------------------------------------------------------------------
// K3: global L2 normalization per b
// ---------------------------------------------------------------------------
__global__ __launch_bounds__(256) void k_scale(
    float* __restrict__ out, const float* __restrict__ gsum_part)
{
    int idx = blockIdx.x * 256 + threadIdx.x;   // each handles one float4
    size_t f = (size_t)idx * 4;
    int b = (int)(f >> 15);                     // D*K = 32768 per b
    float s = gsum_part[b * 4 + 0] + gsum_part[b * 4 + 1] +
              gsum_part[b * 4 + 2] + gsum_part[b * 4 + 3];
    float scale = 1.f / fmaxf(sqrtf(s), 1e-12f);
    float4 v = *(float4*)(out + f);
    v.x *= scale; v.y *= scale; v.z *= scale; v.w *= scale;
    *(float4*)(out + f) = v;
}

extern "C" void kernel_launch(void* const* d_in, const int* in_sizes, int n_in,
                              void* d_out, int out_size, void* d_ws, size_t ws_size,
                              hipStream_t stream)
{
    const float* x        = (const float*)d_in[0];
    const float* clusters = (const float*)d_in[1];
    const float* rmean    = (const float*)d_in[2];
    const float* rvar     = (const float*)d_in[3];
    const float* c2       = (const float*)d_in[4];
    float* out = (float*)d_out;

    // workspace layout (floats): assign | asum_part | a_sum | gsum_part
    float* assign    = (float*)d_ws;                         // B*N*K = 4194304
    float* asum_part = assign + (size_t)BB * NN * KK;        // 512*64 = 32768
    float* a_sum     = asum_part + (size_t)512 * KK;         // 4096
    float* gsum_part = a_sum + (size_t)BB * KK;              // 256

    k_assign<<<512, 256, 0, stream>>>(x, clusters, rmean, rvar, assign, asum_part);
    k_asum_reduce<<<16, 256, 0, stream>>>(asum_part, a_sum);
    k_vlad<<<256, 256, 0, stream>>>(x, assign, a_sum, c2, out, gsum_part);
    k_scale<<<2048, 256, 0, stream>>>(out, gsum_part);
}

// Round 2
// 171.517 us; speedup vs baseline: 1.2988x; 1.2988x over previous
//
#include <hip/hip_runtime.h>
#include <math.h>

// NetVLAD: B=64, N=1024, D=512, K=64, G=16 (C=80)
#define BB 64
#define NN 1024
#define DD 512
#define KK 64
#define CC 80

// ---------------------------------------------------------------------------
// K1: scores = x @ clusters, BN(running stats), softmax over 80, keep first 64
//     -> assign (B*N, 64), per-block column sums -> asum_part
// Block: 256 threads, tile 128 rows x 80 cols, K-chunks of 32.
// x-tile stored TRANSPOSED (xs_t[d][row], stride 132) so the per-d A-fragment
// read is 2 broadcast ds_read_b128 instead of 8 scalar ds_read_b32.
// ---------------------------------------------------------------------------
__global__ __launch_bounds__(256) void k_assign(
    const float* __restrict__ x,         // (B*N, D)
    const float* __restrict__ clusters,  // (D, C)
    const float* __restrict__ rmean,     // (C)
    const float* __restrict__ rvar,      // (C)
    float* __restrict__ assign,          // (B*N, K)
    float* __restrict__ asum_part)       // (512, K) per-block partials
{
    union Sm {
        struct { float xs_t[32][132]; float cs[32][81]; } g;     // GEMM tiles
        struct { float ss[128][81]; float rmax[128]; float rinv[128]; } s; // softmax
    };
    __shared__ Sm sm;
    __shared__ float bnm[CC], bns[CC];
    __shared__ float colp[4][64];

    const int t = threadIdx.x;
    const int row0 = blockIdx.x * 128;   // 128 rows per block; 8 blocks per b

    if (t < CC) {
        bnm[t] = rmean[t];
        bns[t] = rsqrtf(rvar[t] + 1e-5f);
    }

    const int ty = t >> 4;   // 0..15 -> rows ty*8..ty*8+7
    const int tx = t & 15;   // 0..15 -> cols tx*5..tx*5+4

    float acc[8][5];
#pragma unroll
    for (int i = 0; i < 8; ++i)
#pragma unroll
        for (int j = 0; j < 5; ++j) acc[i][j] = 0.f;

    for (int d0 = 0; d0 < DD; d0 += 32) {
        __syncthreads();
        // x tile: 128 rows x 32 d, stored transposed
#pragma unroll
        for (int i = 0; i < 4; ++i) {
            int f = t + i * 256;
            int r = f >> 3, dq = f & 7;
            float4 v = *(const float4*)(x + (size_t)(row0 + r) * DD + d0 + dq * 4);
            sm.g.xs_t[dq * 4 + 0][r] = v.x;
            sm.g.xs_t[dq * 4 + 1][r] = v.y;
            sm.g.xs_t[dq * 4 + 2][r] = v.z;
            sm.g.xs_t[dq * 4 + 3][r] = v.w;
        }
        // clusters tile: 32 d x 80 c = 640 float4
        for (int f = t; f < 640; f += 256) {
            int d = f / 20, cq = f % 20;
            float4 v = *(const float4*)(clusters + (size_t)(d0 + d) * CC + cq * 4);
            sm.g.cs[d][cq * 4 + 0] = v.x;
            sm.g.cs[d][cq * 4 + 1] = v.y;
            sm.g.cs[d][cq * 4 + 2] = v.z;
            sm.g.cs[d][cq * 4 + 3] = v.w;
        }
        __syncthreads();
#pragma unroll 4
        for (int d = 0; d < 32; ++d) {
            float4 a0 = *(const float4*)&sm.g.xs_t[d][ty * 8];
            float4 a1 = *(const float4*)&sm.g.xs_t[d][ty * 8 + 4];
            float a[8] = {a0.x, a0.y, a0.z, a0.w, a1.x, a1.y, a1.z, a1.w};
            float bv[5];
#pragma unroll
            for (int j = 0; j < 5; ++j) bv[j] = sm.g.cs[d][tx * 5 + j];
#pragma unroll
            for (int i = 0; i < 8; ++i)
#pragma unroll
                for (int j = 0; j < 5; ++j)
                    acc[i][j] = fmaf(a[i], bv[j], acc[i][j]);
        }
    }
    __syncthreads();   // GEMM tiles dead; reuse LDS for scores

    // BN transform, stage scores
#pragma unroll
    for (int i = 0; i < 8; ++i) {
        int r = ty * 8 + i;
#pragma unroll
        for (int j = 0; j < 5; ++j) {
            int c = tx * 5 + j;
            sm.s.ss[r][c] = (acc[i][j] - bnm[c]) * bns[c];
        }
    }
    __syncthreads();
    // per-row max & 1/sum over all 80 clusters
    if (t < 128) {
        float m = -1e30f;
        for (int c = 0; c < CC; ++c) m = fmaxf(m, sm.s.ss[t][c]);
        float sum = 0.f;
        for (int c = 0; c < CC; ++c) sum += __expf(sm.s.ss[t][c] - m);
        sm.s.rmax[t] = m;
        sm.s.rinv[t] = 1.f / sum;
    }
    __syncthreads();
    // write assign (first 64 cols) coalesced + column partial sums
    const int kcol = t & 63;
    const int rg = t >> 6;   // 0..3
    float csum = 0.f;
#pragma unroll 4
    for (int rr = 0; rr < 32; ++rr) {
        int r = rg + rr * 4;
        float v = __expf(sm.s.ss[r][kcol] - sm.s.rmax[r]) * sm.s.rinv[r];
        assign[(size_t)(row0 + r) * KK + kcol] = v;
        csum += v;
    }
    colp[rg][kcol] = csum;
    __syncthreads();
    if (t < 64) {
        float s = colp[0][t] + colp[1][t] + colp[2][t] + colp[3][t];
        asum_part[(size_t)blockIdx.x * KK + t] = s;
    }
}

// ---------------------------------------------------------------------------
// K1b: a_sum[b,k] = sum of 8 row-tile partials (deterministic, no atomics)
// ---------------------------------------------------------------------------
__global__ __launch_bounds__(256) void k_asum_reduce(
    const float* __restrict__ asum_part, float* __restrict__ a_sum)
{
    int i = blockIdx.x * 256 + threadIdx.x;   // 4096 = B*K
    if (i >= BB * KK) return;
    int b = i >> 6, k = i & 63;
    float s = 0.f;
#pragma unroll
    for (int tile = 0; tile < 8; ++tile)
        s += asum_part[(size_t)(b * 8 + tile) * KK + k];
    a_sum[i] = s;
}

// ---------------------------------------------------------------------------
// K2a: partial vlad GEMM over an N-chunk of 256.
// Block = (b, d-tile of 128, n-chunk of 4). 1024 blocks, 256 threads, acc[8][4].
// LDS tiles UNPADDED: float4 staging writes are then exactly linear
// (conflict-free); reads are broadcast (as) or row-internal (xs).
// ---------------------------------------------------------------------------
__global__ __launch_bounds__(256) void k_vlad_part(
    const float* __restrict__ x,       // (B*N, D)
    const float* __restrict__ assign,  // (B*N, K)
    float* __restrict__ part)          // (1024, 64*128)
{
    __shared__ float as[32][64];
    __shared__ float xs[32][128];

    const int t = threadIdx.x;
    const int b  = blockIdx.x >> 4;
    const int dt = (blockIdx.x >> 2) & 3;
    const int nc = blockIdx.x & 3;
    const int d0 = dt * 128;

    const int tx = t & 31;   // d cols tx*4..+3
    const int ty = t >> 5;   // 0..7 -> k rows ty*8..+7

    float acc[8][4];
#pragma unroll
    for (int i = 0; i < 8; ++i)
#pragma unroll
        for (int j = 0; j < 4; ++j) acc[i][j] = 0.f;

    const size_t xbase = (size_t)b * NN * DD + d0;
    const size_t abase = (size_t)b * NN * KK;
    const int nbeg = nc * 256;

    for (int n0 = nbeg; n0 < nbeg + 256; n0 += 32) {
        __syncthreads();
        // assign tile 32 x 64 = 512 float4 (linear writes)
#pragma unroll
        for (int i = 0; i < 2; ++i) {
            int f = t + i * 256;
            int n = f >> 4, kq = f & 15;
            *(float4*)&as[n][kq * 4] =
                *(const float4*)(assign + abase + (size_t)(n0 + n) * KK + kq * 4);
        }
        // x tile 32 x 128 = 1024 float4 (linear writes)
#pragma unroll
        for (int i = 0; i < 4; ++i) {
            int f = t + i * 256;
            int n = f >> 5, dq = f & 31;
            *(float4*)&xs[n][dq * 4] =
                *(const float4*)(x + xbase + (size_t)(n0 + n) * DD + dq * 4);
        }
        __syncthreads();
#pragma unroll 4
        for (int n = 0; n < 32; ++n) {
            float4 a0 = *(const float4*)&as[n][ty * 8];
            float4 a1 = *(const float4*)&as[n][ty * 8 + 4];
            float4 bv = *(const float4*)&xs[n][tx * 4];
            float a[8] = {a0.x, a0.y, a0.z, a0.w, a1.x, a1.y, a1.z, a1.w};
            float bb[4] = {bv.x, bv.y, bv.z, bv.w};
#pragma unroll
            for (int i = 0; i < 8; ++i)
#pragma unroll
                for (int j = 0; j < 4; ++j)
                    acc[i][j] = fmaf(a[i], bb[j], acc[i][j]);
        }
    }
    // write partial tile: (k, d) row-major, float4 coalesced
    float* p = part + (size_t)blockIdx.x * (KK * 128);
#pragma unroll
    for (int i = 0; i < 8; ++i)
        *(float4*)(p + (size_t)(ty * 8 + i) * 128 + tx * 4) =
            make_float4(acc[i][0], acc[i][1], acc[i][2], acc[i][3]);
}

// ---------------------------------------------------------------------------
// K2b: reduce 4 N-chunk partials, subtract a_sum*c2, intra-norm over k,
//      staged coalesced write, global-sumsq partial. 256 blocks (b, dtile).
// ---------------------------------------------------------------------------
__global__ __launch_bounds__(256) void k_vlad_fin(
    const float* __restrict__ part,    // (1024, 64*128)
    const float* __restrict__ a_sum,   // (B, K)
    const float* __restrict__ c2,      // (K, D)
    float* __restrict__ out,           // (B, D*K)
    float* __restrict__ gsum_part)     // (B*4)
{
    __shared__ float red[8][128];
    __shared__ float sc[128];
    __shared__ float ot[128][65];

    const int t = threadIdx.x;
    const int b = blockIdx.x >> 2;
    const int dt = blockIdx.x & 3;
    const int d0 = dt * 128;

    const int tx = t & 31;   // d cols tx*4..+3
    const int ty = t >> 5;   // 0..7 -> k rows ty*8..+7

    const float* p0 = part + (size_t)blockIdx.x * 4 * (KK * 128);

    float val[8][4];
#pragma unroll
    for (int i = 0; i < 8; ++i) {
        int k = ty * 8 + i;
        float4 s = make_float4(0.f, 0.f, 0.f, 0.f);
#pragma unroll
        for (int nc = 0; nc < 4; ++nc) {
            float4 v = *(const float4*)(p0 + (size_t)nc * (KK * 128) +
                                        (size_t)k * 128 + tx * 4);
            s.x += v.x; s.y += v.y; s.z += v.z; s.w += v.w;
        }
        float asv = a_sum[b * KK + k];
        float4 cv = *(const float4*)(c2 + (size_t)k * DD + d0 + tx * 4);
        val[i][0] = s.x - asv * cv.x;
        val[i][1] = s.y - asv * cv.y;
        val[i][2] = s.z - asv * cv.z;
        val[i][3] = s.w - asv * cv.w;
    }
    // per-d sum of squares over k: 8 ty-group partials, then reduce
    float p[4] = {0.f, 0.f, 0.f, 0.f};
#pragma unroll
    for (int i = 0; i < 8; ++i)
#pragma unroll
        for (int j = 0; j < 4; ++j) p[j] += val[i][j] * val[i][j];
    *(float4*)&red[ty][tx * 4] = make_float4(p[0], p[1], p[2], p[3]);
    __syncthreads();
    if (t < 128) {
        float s = 0.f;
#pragma unroll
        for (int g = 0; g < 8; ++g) s += red[g][t];
        float scale = 1.f / fmaxf(sqrtf(s), 1e-12f);
        sc[t] = scale;
        red[0][t] = s * scale * scale;  // column contribution to global sumsq
    }
    __syncthreads();
    if (t == 0) {
        float s = 0.f;
        for (int d = 0; d < 128; ++d) s += red[0][d];
        gsum_part[blockIdx.x] = s;
    }
    // scale + stage transposed (d-major, k-minor) for coalesced write
#pragma unroll
    for (int i = 0; i < 8; ++i)
#pragma unroll
        for (int j = 0; j < 4; ++j)
            ot[tx * 4 + j][ty * 8 + i] = val[i][j] * sc[tx * 4 + j];
    __syncthreads();
    const size_t obase = (size_t)b * (DD * KK) + (size_t)d0 * KK;
#pragma unroll
    for (int i = 0; i < 32; ++i) {
        int f = t + i * 256;
        out[obase + f] = ot[f >> 6][f & 63];
    }
}

// ---------------------------------------------------------------------------
// K3: global L2 normalization per b
// ---------------------------------------------------------------------------
__global__ __launch_bounds__(256) void k_scale(
    float* __restrict__ out, const float* __restrict__ gsum_part)
{
    int idx = blockIdx.x * 256 + threadIdx.x;   // each handles one float4
    size_t f = (size_t)idx * 4;
    int b = (int)(f >> 15);                     // D*K = 32768 per b
    float s = gsum_part[b * 4 + 0] + gsum_part[b * 4 + 1] +
              gsum_part[b * 4 + 2] + gsum_part[b * 4 + 3];
    float scale = 1.f / fmaxf(sqrtf(s), 1e-12f);
    float4 v = *(float4*)(out + f);
    v.x *= scale; v.y *= scale; v.z *= scale; v.w *= scale;
    *(float4*)(out + f) = v;
}

extern "C" void kernel_launch(void* const* d_in, const int* in_sizes, int n_in,
                              void* d_out, int out_size, void* d_ws, size_t ws_size,
                              hipStream_t stream)
{
    const float* x        = (const float*)d_in[0];
    const float* clusters = (const float*)d_in[1];
    const float* rmean    = (const float*)d_in[2];
    const float* rvar     = (const float*)d_in[3];
    const float* c2       = (const float*)d_in[4];
    float* out = (float*)d_out;

    // workspace layout (floats): assign | asum_part | a_sum | gsum_part | part
    float* assign    = (float*)d_ws;                         // B*N*K = 4194304
    float* asum_part = assign + (size_t)BB * NN * KK;        // 512*64 = 32768
    float* a_sum     = asum_part + (size_t)512 * KK;         // 4096
    float* gsum_part = a_sum + (size_t)BB * KK;              // 256
    float* part      = gsum_part + 256;                      // 1024*8192 = 8388608

    k_assign<<<512, 256, 0, stream>>>(x, clusters, rmean, rvar, assign, asum_part);
    k_asum_reduce<<<16, 256, 0, stream>>>(asum_part, a_sum);
    k_vlad_part<<<1024, 256, 0, stream>>>(x, assign, part);
    k_vlad_fin<<<256, 256, 0, stream>>>(part, a_sum, c2, out, gsum_part);
    k_scale<<<2048, 256, 0, stream>>>(out, gsum_part);
}

// Round 3
// 120.893 us; speedup vs baseline: 1.8426x; 1.4188x over previous
//
#include <hip/hip_runtime.h>
#include <math.h>

// NetVLAD: B=64, N=1024, D=512, K=64, G=16 (C=80)
#define BB 64
#define NN 1024
#define DD 512
#define KK 64
#define CC 80

typedef __attribute__((ext_vector_type(8))) short short8;  // 8 bf16 (4 VGPRs)
typedef __attribute__((ext_vector_type(4))) float f32x4;   // MFMA accumulator

union U16x8 { uint4 u; short8 s; };

// Split fp32 -> bf16 hi (truncated) + bf16 lo (truncated remainder).
// Per-product error ~2^-16 when used as hi*hi + lo*hi + hi*lo.
__device__ __forceinline__ void cvt_hilo8(const float* f, short8& hi, short8& lo) {
#pragma unroll
    for (int j = 0; j < 8; ++j) {
        unsigned u = __float_as_uint(f[j]);
        unsigned uh = u & 0xFFFF0000u;
        float fl = f[j] - __uint_as_float(uh);
        hi[j] = (short)(uh >> 16);
        lo[j] = (short)(__float_as_uint(fl) >> 16);
    }
}

// ---------------------------------------------------------------------------
// K0: pre-swizzle clusters (512x80 fp32) into per-lane MFMA B-frag layout,
// bf16 hi/lo. Entry (ks,q,l,dw): q = tile*2+part; c = tile*16+(l&15);
// d = ks*32+(l>>4)*8+dw*2+{0,1}. 40960 dwords = 160KB.
// ---------------------------------------------------------------------------
__global__ __launch_bounds__(256) void k_prep(
    const float* __restrict__ clusters, unsigned int* __restrict__ bfrag)
{
    int i = blockIdx.x * 256 + threadIdx.x;
    if (i >= 16 * 10 * 64 * 4) return;
    int dw = i & 3;
    int l = (i >> 2) & 63;
    int rest = i >> 8;           // 0..159
    int q = rest % 10;
    int ks = rest / 10;
    int tile = q >> 1, part = q & 1;
    int c = tile * 16 + (l & 15);
    int dbase = ks * 32 + (l >> 4) * 8 + dw * 2;
    unsigned outw = 0;
#pragma unroll
    for (int e = 0; e < 2; ++e) {
        float v = clusters[(size_t)(dbase + e) * CC + c];
        unsigned u = __float_as_uint(v);
        unsigned uh = u & 0xFFFF0000u;
        unsigned h;
        if (part == 0) h = uh >> 16;
        else {
            float fl = v - __uint_as_float(uh);
            h = __float_as_uint(fl) >> 16;
        }
        outw |= h << (16 * e);
    }
    bfrag[i] = outw;
}

// ---------------------------------------------------------------------------
// K1: scores = x @ clusters via split-bf16 MFMA (16x16x32), BN, softmax(80),
// keep first 64 -> assign + per-block column sums. Block = 64 rows, 4 waves,
// wave w owns rows row0+w*16..+15. No LDS / no barriers in the main loop:
// A-frags from global x (convert in regs), B-frags from pre-swizzled L2 buf.
// C/D layout: col = lane&15 (cluster), row = (lane>>4)*4 + reg (x-row).
// ---------------------------------------------------------------------------
__global__ __launch_bounds__(256) void k_assign_mfma(
    const float* __restrict__ x,           // (B*N, D)
    const unsigned int* __restrict__ bfrag,
    const float* __restrict__ rmean,
    const float* __restrict__ rvar,
    float* __restrict__ assign,            // (B*N, K)
    float* __restrict__ asum_part)         // (1024, K)
{
    __shared__ float ss[64][65];
    __shared__ float colp[4][64];
    __shared__ float bnm[CC], bns[CC];

    const int t = threadIdx.x;
    const int w = t >> 6;       // wave 0..3
    const int l = t & 63;       // lane
    const int row0 = blockIdx.x * 64;

    if (t < CC) {
        bnm[t] = rmean[t];
        bns[t] = rsqrtf(rvar[t] + 1e-5f);
    }

    f32x4 acc[5];
#pragma unroll
    for (int nt = 0; nt < 5; ++nt)
#pragma unroll
        for (int r = 0; r < 4; ++r) acc[nt][r] = 0.f;

    const float* xp = x + (size_t)(row0 + w * 16 + (l & 15)) * DD + (l >> 4) * 8;
    const uint4* bbase = (const uint4*)bfrag + l;

#pragma unroll 2
    for (int ks = 0; ks < 16; ++ks) {
        float4 v0 = *(const float4*)(xp + ks * 32);
        float4 v1 = *(const float4*)(xp + ks * 32 + 4);
        float f[8] = {v0.x, v0.y, v0.z, v0.w, v1.x, v1.y, v1.z, v1.w};
        short8 ah, al;
        cvt_hilo8(f, ah, al);
        const uint4* bp = bbase + (size_t)(ks * 10) * 64;
#pragma unroll
        for (int nt = 0; nt < 5; ++nt) {
            U16x8 uh, ul;
            uh.u = bp[(nt * 2 + 0) * 64];
            ul.u = bp[(nt * 2 + 1) * 64];
            acc[nt] = __builtin_amdgcn_mfma_f32_16x16x32_bf16(ah, uh.s, acc[nt], 0, 0, 0);
            acc[nt] = __builtin_amdgcn_mfma_f32_16x16x32_bf16(al, uh.s, acc[nt], 0, 0, 0);
            acc[nt] = __builtin_amdgcn_mfma_f32_16x16x32_bf16(ah, ul.s, acc[nt], 0, 0, 0);
        }
    }

    __syncthreads();   // bn tables ready; LDS epilogue begins

    // BN + softmax per row, fully in-register (rows spread over 16-lane groups)
    float a[4][4];
#pragma unroll
    for (int r = 0; r < 4; ++r) {
        float sc[5];
#pragma unroll
        for (int nt = 0; nt < 5; ++nt) {
            int c = nt * 16 + (l & 15);
            sc[nt] = (acc[nt][r] - bnm[c]) * bns[c];
        }
        float m = sc[0];
#pragma unroll
        for (int nt = 1; nt < 5; ++nt) m = fmaxf(m, sc[nt]);
        m = fmaxf(m, __shfl_xor(m, 1));
        m = fmaxf(m, __shfl_xor(m, 2));
        m = fmaxf(m, __shfl_xor(m, 4));
        m = fmaxf(m, __shfl_xor(m, 8));
        float p[5], sum = 0.f;
#pragma unroll
        for (int nt = 0; nt < 5; ++nt) { p[nt] = __expf(sc[nt] - m); sum += p[nt]; }
        sum += __shfl_xor(sum, 1);
        sum += __shfl_xor(sum, 2);
        sum += __shfl_xor(sum, 4);
        sum += __shfl_xor(sum, 8);
        float rinv = 1.f / sum;
#pragma unroll
        for (int nt = 0; nt < 4; ++nt) a[nt][r] = p[nt] * rinv;
    }
    // stage assign to LDS + per-wave column sums
#pragma unroll
    for (int nt = 0; nt < 4; ++nt) {
        float cs = a[nt][0] + a[nt][1] + a[nt][2] + a[nt][3];
        cs += __shfl_xor(cs, 16);
        cs += __shfl_xor(cs, 32);
        if (l < 16) colp[w][nt * 16 + l] = cs;
#pragma unroll
        for (int r = 0; r < 4; ++r)
            ss[w * 16 + (l >> 4) * 4 + r][nt * 16 + (l & 15)] = a[nt][r];
    }
    __syncthreads();
    // coalesced assign write
    const int c = t & 63;
#pragma unroll
    for (int i = 0; i < 16; ++i) {
        int r = w + i * 4;
        assign[(size_t)(row0 + r) * KK + c] = ss[r][c];
    }
    if (t < 64) {
        asum_part[(size_t)blockIdx.x * KK + t] =
            colp[0][t] + colp[1][t] + colp[2][t] + colp[3][t];
    }
}

// ---------------------------------------------------------------------------
// K1b: a_sum[b,k] = sum of 16 row-tile partials
// ---------------------------------------------------------------------------
__global__ __launch_bounds__(256) void k_asum_reduce(
    const float* __restrict__ asum_part, float* __restrict__ a_sum)
{
    int i = blockIdx.x * 256 + threadIdx.x;   // 4096 = B*K
    if (i >= BB * KK) return;
    int b = i >> 6, k = i & 63;
    float s = 0.f;
#pragma unroll
    for (int tile = 0; tile < 16; ++tile)
        s += asum_part[(size_t)(b * 16 + tile) * KK + k];
    a_sum[i] = s;
}

// ---------------------------------------------------------------------------
// K2a: partial vlad GEMM over an N-chunk of 256.
// Block = (b, d-tile of 128, n-chunk of 4). 1024 blocks, 256 threads.
// ---------------------------------------------------------------------------
__global__ __launch_bounds__(256) void k_vlad_part(
    const float* __restrict__ x,       // (B*N, D)
    const float* __restrict__ assign,  // (B*N, K)
    float* __restrict__ part)          // (1024, 64*128)
{
    __shared__ float as[32][64];
    __shared__ float xs[32][128];

    const int t = threadIdx.x;
    const int b  = blockIdx.x >> 4;
    const int dt = (blockIdx.x >> 2) & 3;
    const int nc = blockIdx.x & 3;
    const int d0 = dt * 128;

    const int tx = t & 31;   // d cols tx*4..+3
    const int ty = t >> 5;   // 0..7 -> k rows ty*8..+7

    float acc[8][4];
#pragma unroll
    for (int i = 0; i < 8; ++i)
#pragma unroll
        for (int j = 0; j < 4; ++j) acc[i][j] = 0.f;

    const size_t xbase = (size_t)b * NN * DD + d0;
    const size_t abase = (size_t)b * NN * KK;
    const int nbeg = nc * 256;

    for (int n0 = nbeg; n0 < nbeg + 256; n0 += 32) {
        __syncthreads();
#pragma unroll
        for (int i = 0; i < 2; ++i) {
            int f = t + i * 256;
            int n = f >> 4, kq = f & 15;
            *(float4*)&as[n][kq * 4] =
                *(const float4*)(assign + abase + (size_t)(n0 + n) * KK + kq * 4);
        }
#pragma unroll
        for (int i = 0; i < 4; ++i) {
            int f = t + i * 256;
            int n = f >> 5, dq = f & 31;
            *(float4*)&xs[n][dq * 4] =
                *(const float4*)(x + xbase + (size_t)(n0 + n) * DD + dq * 4);
        }
        __syncthreads();
#pragma unroll 4
        for (int n = 0; n < 32; ++n) {
            float4 a0 = *(const float4*)&as[n][ty * 8];
            float4 a1 = *(const float4*)&as[n][ty * 8 + 4];
            float4 bv = *(const float4*)&xs[n][tx * 4];
            float a[8] = {a0.x, a0.y, a0.z, a0.w, a1.x, a1.y, a1.z, a1.w};
            float bb[4] = {bv.x, bv.y, bv.z, bv.w};
#pragma unroll
            for (int i = 0; i < 8; ++i)
#pragma unroll
                for (int j = 0; j < 4; ++j)
                    acc[i][j] = fmaf(a[i], bb[j], acc[i][j]);
        }
    }
    float* p = part + (size_t)blockIdx.x * (KK * 128);
#pragma unroll
    for (int i = 0; i < 8; ++i)
        *(float4*)(p + (size_t)(ty * 8 + i) * 128 + tx * 4) =
            make_float4(acc[i][0], acc[i][1], acc[i][2], acc[i][3]);
}

// ---------------------------------------------------------------------------
// K2b: reduce 4 N-chunk partials, subtract a_sum*c2, intra-norm over k,
//      staged coalesced write, global-sumsq partial. 256 blocks (b, dtile).
// ---------------------------------------------------------------------------
__global__ __launch_bounds__(256) void k_vlad_fin(
    const float* __restrict__ part,    // (1024, 64*128)
    const float* __restrict__ a_sum,   // (B, K)
    const float* __restrict__ c2,      // (K, D)
    float* __restrict__ out,           // (B, D*K)
    float* __restrict__ gsum_part)     // (B*4)
{
    __shared__ float red[8][128];
    __shared__ float sc[128];
    __shared__ float ot[128][65];

    const int t = threadIdx.x;
    const int b = blockIdx.x >> 2;
    const int dt = blockIdx.x & 3;
    const int d0 = dt * 128;

    const int tx = t & 31;
    const int ty = t >> 5;

    const float* p0 = part + (size_t)blockIdx.x * 4 * (KK * 128);

    float val[8][4];
#pragma unroll
    for (int i = 0; i < 8; ++i) {
        int k = ty * 8 + i;
        float4 s = make_float4(0.f, 0.f, 0.f, 0.f);
#pragma unroll
        for (int nc = 0; nc < 4; ++nc) {
            float4 v = *(const float4*)(p0 + (size_t)nc * (KK * 128) +
                                        (size_t)k * 128 + tx * 4);
            s.x += v.x; s.y += v.y; s.z += v.z; s.w += v.w;
        }
        float asv = a_sum[b * KK + k];
        float4 cv = *(const float4*)(c2 + (size_t)k * DD + d0 + tx * 4);
        val[i][0] = s.x - asv * cv.x;
        val[i][1] = s.y - asv * cv.y;
        val[i][2] = s.z - asv * cv.z;
        val[i][3] = s.w - asv * cv.w;
    }
    float p[4] = {0.f, 0.f, 0.f, 0.f};
#pragma unroll
    for (int i = 0; i < 8; ++i)
#pragma unroll
        for (int j = 0; j < 4; ++j) p[j] += val[i][j] * val[i][j];
    *(float4*)&red[ty][tx * 4] = make_float4(p[0], p[1], p[2], p[3]);
    __syncthreads();
    if (t < 128) {
        float s = 0.f;
#pragma unroll
        for (int g = 0; g < 8; ++g) s += red[g][t];
        float scale = 1.f / fmaxf(sqrtf(s), 1e-12f);
        sc[t] = scale;
        red[0][t] = s * scale * scale;
    }
    __syncthreads();
    if (t == 0) {
        float s = 0.f;
        for (int d = 0; d < 128; ++d) s += red[0][d];
        gsum_part[blockIdx.x] = s;
    }
#pragma unroll
    for (int i = 0; i < 8; ++i)
#pragma unroll
        for (int j = 0; j < 4; ++j)
            ot[tx * 4 + j][ty * 8 + i] = val[i][j] * sc[tx * 4 + j];
    __syncthreads();
    const size_t obase = (size_t)b * (DD * KK) + (size_t)d0 * KK;
#pragma unroll
    for (int i = 0; i < 32; ++i) {
        int f = t + i * 256;
        out[obase + f] = ot[f >> 6][f & 63];
    }
}

// ---------------------------------------------------------------------------
// K3: global L2 normalization per b
// ---------------------------------------------------------------------------
__global__ __launch_bounds__(256) void k_scale(
    float* __restrict__ out, const float* __restrict__ gsum_part)
{
    int idx = blockIdx.x * 256 + threadIdx.x;
    size_t f = (size_t)idx * 4;
    int b = (int)(f >> 15);                     // D*K = 32768 per b
    float s = gsum_part[b * 4 + 0] + gsum_part[b * 4 + 1] +
              gsum_part[b * 4 + 2] + gsum_part[b * 4 + 3];
    float scale = 1.f / fmaxf(sqrtf(s), 1e-12f);
    float4 v = *(float4*)(out + f);
    v.x *= scale; v.y *= scale; v.z *= scale; v.w *= scale;
    *(float4*)(out + f) = v;
}

extern "C" void kernel_launch(void* const* d_in, const int* in_sizes, int n_in,
                              void* d_out, int out_size, void* d_ws, size_t ws_size,
                              hipStream_t stream)
{
    const float* x        = (const float*)d_in[0];
    const float* clusters = (const float*)d_in[1];
    const float* rmean    = (const float*)d_in[2];
    const float* rvar     = (const float*)d_in[3];
    const float* c2       = (const float*)d_in[4];
    float* out = (float*)d_out;

    // workspace (floats): assign | asum_part | a_sum | gsum_part | part
    // bfrag (160KB) ALIASES part: k_prep writes it, k_assign reads it,
    // k_vlad_part overwrites it later (stream-ordered, deterministic).
    float* assign    = (float*)d_ws;                         // 4194304
    float* asum_part = assign + (size_t)BB * NN * KK;        // 1024*64
    float* a_sum     = asum_part + (size_t)1024 * KK;        // 4096
    float* gsum_part = a_sum + (size_t)BB * KK;              // 256
    float* part      = gsum_part + 256;                      // 1024*8192
    unsigned int* bfrag = (unsigned int*)part;               // 40960 dwords

    k_prep<<<160, 256, 0, stream>>>(clusters, bfrag);
    k_assign_mfma<<<1024, 256, 0, stream>>>(x, bfrag, rmean, rvar, assign, asum_part);
    k_asum_reduce<<<16, 256, 0, stream>>>(asum_part, a_sum);
    k_vlad_part<<<1024, 256, 0, stream>>>(x, assign, part);
    k_vlad_fin<<<256, 256, 0, stream>>>(part, a_sum, c2, out, gsum_part);
    k_scale<<<2048, 256, 0, stream>>>(out, gsum_part);
}